// Round 12
// baseline (132.554 us; speedup 1.0000x reference)
//
#include <hip/hip_runtime.h>

#define NN 64000
#define NG 512
#define NPG 125
#define DIM 128
#define NC 10
#define SHID 69
#define NF 16
#define PHID 8
#define ELPAD 132   // E rows padded 128->132 in LDS (k_E_tail)
#define TSTR 85     // Ts row stride (odd -> conflict-free)
#define PSTR 41     // Ps row stride (odd -> conflict-free)
#define EPSTR 11    // Epart per-d stride (odd -> conflict-free)

// output float offsets (concatenated tuple, row-major)
#define OFF_PRED1 0
#define OFF_PRED2 1024
#define OFF_IND   2048
#define OFF_S     2560
#define OFF_E     642560
#define OFF_Q     1297920

typedef __attribute__((ext_vector_type(8))) short short8;   // 8 bf16 (4 VGPRs)
typedef __attribute__((ext_vector_type(4))) float f32x4;    // MFMA C/D

// ---------------- threefry2x32 (JAX-exact, key = (0, 42)) ----------------
__device__ __forceinline__ unsigned rotl32(unsigned x, int r) {
    return (x << r) | (x >> (32 - r));
}

__device__ __forceinline__ void threefry_0_42(unsigned x0, unsigned x1,
                                              unsigned& o0, unsigned& o1) {
    const unsigned k0 = 0u, k1 = 42u;
    const unsigned k2 = k0 ^ k1 ^ 0x1BD11BDAu;
    unsigned ks[3] = {k0, k1, k2};
    const int R0[4] = {13, 15, 26, 6};
    const int R1[4] = {17, 29, 16, 24};
    x0 += k0; x1 += k1;
    #pragma unroll
    for (int i = 0; i < 5; i++) {
        const int* R = (i & 1) ? R1 : R0;
        #pragma unroll
        for (int r = 0; r < 4; r++) {
            x0 += x1;
            x1 = rotl32(x1, R[r]);
            x1 ^= x0;
        }
        x0 += ks[(i + 1) % 3];
        x1 += ks[(i + 2) % 3] + (unsigned)(i + 1);
    }
    o0 = x0; o1 = x1;
}

// jax_threefry_partitionable: element i -> counter (0, i); bits = o0 ^ o1. (verified R2)
__device__ __forceinline__ unsigned random_bits_partitionable(unsigned i) {
    unsigned o0, o1;
    threefry_0_42(0u, i, o0, o1);
    return o0 ^ o1;
}

__device__ __forceinline__ float gumbel_from_bits(unsigned bits) {
    float f = __uint_as_float((bits >> 9) | 0x3f800000u) - 1.0f;  // [0,1)
    if (f <= 0.0f) f = 1.1754943508222875e-38f;                   // minval=tiny
    return -logf(-logf(f));
}

#define R10(M) M(0) M(1) M(2) M(3) M(4) M(5) M(6) M(7) M(8) M(9)

// ---------------- K0: pre-split w1 into hi/lo bf16 B-fragments in d_ws ----------------
// slot s = (jt*4+ks)*64 + lane; element i in [0,8): j = jt*16+(l&15),
// k = ks*32+((l>>4)&3)*8+i. Same layout R11's in-block staging used (verified).
__global__ __launch_bounds__(256) void k_split_w1(
    const float* __restrict__ w1, short* __restrict__ fragHi,
    short* __restrict__ fragLo) {
    int e = blockIdx.x * 256 + threadIdx.x;   // < 10240
    int s = e >> 3, i = e & 7;
    int jt = s >> 8, ks = (s >> 6) & 3, l = s & 63;
    int j = jt * 16 + (l & 15);
    int kb = ks * 32 + ((l >> 4) & 3) * 8;
    float x = (j < SHID) ? w1[(kb + i) * SHID + j] : 0.0f;
    unsigned u = __float_as_uint(x);
    short hi = (short)(u >> 16);
    float hf = __uint_as_float(u & 0xFFFF0000u);
    short lo = (short)(__float_as_uint(x - hf) >> 16);
    fragHi[s * 8 + i] = hi;
    fragLo[s * 8 + i] = lo;
}

// ---------------- K1: per-node MLP 128->69(relu)->10 + softmax (split-bf16 MFMA) ----------------
// Block = 64 nodes, 256 threads = 4 waves; wave w owns nodes [w*16, w*16+16).
// B-fragments read DIRECTLY from global d_ws (slot-consecutive -> coalesced,
// L2-hot: all blocks read the same 40 KB). No LDS staging / no first barrier.
// LDS = Ts/Ps only (32 KB -> 4 blocks/CU). Layouts m120/m89-verified (R11 pass).
__global__ __launch_bounds__(256, 4) void k_node_mlp(
    const float* __restrict__ H, const short* __restrict__ fragHi,
    const short* __restrict__ fragLo,
    const float* __restrict__ b1, const float* __restrict__ w2,
    const float* __restrict__ b2, float* __restrict__ S) {
    __shared__ __align__(16) float Ts[64 * TSTR];   // 21760 B
    __shared__ float Ps[64 * PSTR];                 // 10496 B
    int tid = threadIdx.x;
    int w = tid >> 6, l = tid & 63;
    int node = blockIdx.x * 64 + w * 16 + (l & 15);
    const float* Hp = H + (size_t)node * DIM + ((l >> 4) & 3) * 8;

    // ---- A fragments (hi/lo) for 4 k-steps ----
    short8 aHi[4], aLo[4];
    #pragma unroll
    for (int ks = 0; ks < 4; ks++) {
        float4 x0 = *(const float4*)(Hp + ks * 32);
        float4 x1 = *(const float4*)(Hp + ks * 32 + 4);
        float xs[8] = {x0.x, x0.y, x0.z, x0.w, x1.x, x1.y, x1.z, x1.w};
        #pragma unroll
        for (int i = 0; i < 8; i++) {
            unsigned u = __float_as_uint(xs[i]);
            aHi[ks][i] = (short)(u >> 16);
            float lo = xs[i] - __uint_as_float(u & 0xFFFF0000u);
            aLo[ks][i] = (short)(__float_as_uint(lo) >> 16);
        }
    }

    // ---- MFMA: 5 j-tiles x 4 k-steps x 3 (hihi, lohi, hilo) ----
    f32x4 acc[5];
    #pragma unroll
    for (int jt = 0; jt < 5; jt++) {
        f32x4 a = {0.f, 0.f, 0.f, 0.f};
        #pragma unroll
        for (int ks = 0; ks < 4; ks++) {
            int slot = (jt * 4 + ks) * 64 + l;
            short8 bh = *(const short8*)(fragHi + (size_t)slot * 8);
            short8 bl = *(const short8*)(fragLo + (size_t)slot * 8);
            a = __builtin_amdgcn_mfma_f32_16x16x32_bf16(aHi[ks], bh, a, 0, 0, 0);
            a = __builtin_amdgcn_mfma_f32_16x16x32_bf16(aLo[ks], bh, a, 0, 0, 0);
            a = __builtin_amdgcn_mfma_f32_16x16x32_bf16(aHi[ks], bl, a, 0, 0, 0);
        }
        acc[jt] = a;
    }

    // ---- relu(t + b1) into Ts[64][TSTR] (pad j>=69 -> 0) ----
    #pragma unroll
    for (int jt = 0; jt < 5; jt++) {
        int j = jt * 16 + (l & 15);
        float bj = (j < SHID) ? b1[j] : 0.0f;
        #pragma unroll
        for (int r = 0; r < 4; r++) {
            int m = w * 16 + ((l >> 4) & 3) * 4 + r;
            float tv = acc[jt][r];
            Ts[m * TSTR + j] = (j < SHID) ? fmaxf(tv + bj, 0.0f) : 0.0f;
        }
    }
    __syncthreads();

    // ---- layer 2 partials: thread (n = tid&63, q = tid>>6), j in [q*18, q*18+18) ----
    {
        int n = tid & 63, q = tid >> 6;
        float lg[NC] = {};
        for (int jj = 0; jj < 18; jj++) {
            int j = q * 18 + jj;               // < 72; Ts is 0 for j >= 69
            int jx = (j < SHID) ? j : (SHID - 1);
            float tr = Ts[n * TSTR + j];
            const float* w2r = w2 + jx * NC;   // wave-uniform -> s_load
            #pragma unroll
            for (int c = 0; c < NC; c++) lg[c] = fmaf(tr, w2r[c], lg[c]);
        }
        #pragma unroll
        for (int c = 0; c < NC; c++) Ps[n * PSTR + q * NC + c] = lg[c];
    }
    __syncthreads();

    if (tid < 64) {
        int n = tid;
        const float* pr = &Ps[n * PSTR];
        #define LD(c) float s##c = pr[c] + pr[10 + c] + pr[20 + c] + pr[30 + c] + b2[c];
        R10(LD)
        #undef LD
        float m = fmaxf(fmaxf(fmaxf(s0, s1), fmaxf(s2, s3)),
                        fmaxf(fmaxf(fmaxf(s4, s5), fmaxf(s6, s7)), fmaxf(s8, s9)));
        float e0 = expf(s0 - m), e1 = expf(s1 - m), e2 = expf(s2 - m),
              e3 = expf(s3 - m), e4 = expf(s4 - m), e5 = expf(s5 - m),
              e6 = expf(s6 - m), e7 = expf(s7 - m), e8 = expf(s8 - m),
              e9 = expf(s9 - m);
        float ssum = ((e0 + e1) + (e2 + e3)) + ((e4 + e5) + (e6 + e7)) + (e8 + e9);
        float inv = 1.0f / ssum;
        float2* Sp2 = (float2*)(S + ((size_t)blockIdx.x * 64 + n) * NC);
        Sp2[0] = make_float2(e0 * inv, e1 * inv);
        Sp2[1] = make_float2(e2 * inv, e3 * inv);
        Sp2[2] = make_float2(e4 * inv, e5 * inv);
        Sp2[3] = make_float2(e6 * inv, e7 * inv);
        Sp2[4] = make_float2(e8 * inv, e9 * inv);
    }
}

// ---------------- K2: fused E + tail (corr, pred1, sample, Q, fm, pred2) ----------------
// Block = graph, 1024 threads = 8 node-octants x 128 d (8 waves/SIMD worth of
// HBM streams, 8-deep load batching). Epart stride 11 (conflict-free).
// Verified tail on wave 0.
__global__ __launch_bounds__(1024, 4) void k_E_tail(
    const float* __restrict__ H, const float* __restrict__ S,
    const float* __restrict__ wf, const float* __restrict__ bf,
    const int* __restrict__ targets,
    const float* __restrict__ p1, const float* __restrict__ pb1,
    const float* __restrict__ p2, const float* __restrict__ pb2,
    const float* __restrict__ ci, const float* __restrict__ cr,
    float* __restrict__ E, float* __restrict__ pred1, float* __restrict__ pred2,
    float* __restrict__ ind, float* __restrict__ Q) {
    __shared__ __align__(8) float Sl[128 * NC];      // 5120 B (rows >=125 zero)
    __shared__ float Epart[7 * 128 * EPSTR];         // 39424 B, octants 1..7
    __shared__ __align__(16) float El[NC * ELPAD];   // 5280 B
    __shared__ float fmbuf[NC];
    int g = blockIdx.x, tid = threadIdx.x;

    const float* Sg = S + (size_t)g * NPG * NC;
    for (int i = tid; i < 128 * NC; i += 1024) Sl[i] = (i < NPG * NC) ? Sg[i] : 0.0f;
    __syncthreads();

    int q = tid >> 7;       // node octant 0..7 (16 nodes each)
    int d = tid & 127;
    const float* Hg = H + (size_t)g * NPG * DIM + d;

    #define DECLA(c) float a##c = 0.f;
    R10(DECLA)
    #undef DECLA
    int n0 = q * 16;
    #pragma unroll
    for (int ib = 0; ib < 16; ib += 8) {
        float h[8];
        #pragma unroll
        for (int u = 0; u < 8; u++) {
            int nh = min(n0 + ib + u, NPG - 1);   // rows 125..127 have S=0
            h[u] = Hg[(size_t)nh * DIM];
        }
        #pragma unroll
        for (int u = 0; u < 8; u++) {
            const float2* S2 = (const float2*)(Sl + (n0 + ib + u) * NC);
            float2 s01 = S2[0], s23 = S2[1], s45 = S2[2], s67 = S2[3], s89 = S2[4];
            a0 = fmaf(s01.x, h[u], a0); a1 = fmaf(s01.y, h[u], a1);
            a2 = fmaf(s23.x, h[u], a2); a3 = fmaf(s23.y, h[u], a3);
            a4 = fmaf(s45.x, h[u], a4); a5 = fmaf(s45.y, h[u], a5);
            a6 = fmaf(s67.x, h[u], a6); a7 = fmaf(s67.y, h[u], a7);
            a8 = fmaf(s89.x, h[u], a8); a9 = fmaf(s89.y, h[u], a9);
        }
    }
    if (q > 0) {
        float* ep = &Epart[((q - 1) * 128 + d) * EPSTR];
        #define STP(c) ep[c] = a##c;
        R10(STP)
        #undef STP
    }
    __syncthreads();
    if (q == 0) {
        float* Eo = E + (size_t)g * (NC * DIM) + d;
        #pragma unroll
        for (int k = 0; k < 7; k++) {
            const float* ep = &Epart[(k * 128 + d) * EPSTR];
            a0 += ep[0]; a1 += ep[1]; a2 += ep[2]; a3 += ep[3]; a4 += ep[4];
            a5 += ep[5]; a6 += ep[6]; a7 += ep[7]; a8 += ep[8]; a9 += ep[9];
        }
        #define CMB(c) { El[(c) * ELPAD + d] = a##c; Eo[(c) * DIM] = a##c; }
        R10(CMB)
        #undef CMB
    }
    __syncthreads();

    const float2* wf2 = (const float2*)wf;
    int l = tid;
    int samp = 0;
    float corr_lf = 0.f;

    if (tid < 64) {
        // ---- corr: lane l<32 computes corr[i=l>>4][f=l&15] ----
        if (l < 32) {
            int i = l >> 4, f = l & 15;
            float a = ci[f], b = ci[NF + f];
            float mm = fmaxf(a, b);
            float ea = expf(a - mm), eb = expf(b - mm);
            float inter = expf(ci[i * NF + f] - mm) / (ea + eb);
            float mi = -1e30f;
            for (int j = 0; j < NF; j++) mi = fmaxf(mi, cr[i * NF + j]);
            float ri = 0.f;
            for (int j = 0; j < NF; j++) ri += expf(cr[i * NF + j] - mi);
            float intra = expf(cr[i * NF + f] - mi) / ri;
            corr_lf = inter * intra;
        }

        // ---- phase 1: pred1 + softmax + gumbel sample + ind ----
        float a0 = 0.f, a1 = 0.f;
        #pragma unroll
        for (int i = 0; i < 20; i++) {
            int idx = i * 64 + l;
            float e = El[(idx >> 7) * ELPAD + (idx & 127)];
            float2 w = wf2[idx];
            a0 = fmaf(e, w.x, a0);
            a1 = fmaf(e, w.y, a1);
        }
        #pragma unroll
        for (int off = 32; off > 0; off >>= 1) {
            a0 += __shfl_down(a0, off);
            a1 += __shfl_down(a1, off);
        }
        if (l == 0) {
            float y0 = a0 + bf[0], y1 = a1 + bf[1];
            pred1[g * 2] = y0;
            pred1[g * 2 + 1] = y1;
            float m = fmaxf(y0, y1);
            float e0 = expf(y0 - m), e1 = expf(y1 - m), s = e0 + e1;
            float p0 = e0 / s, pp1 = e1 / s;
            float g0 = gumbel_from_bits(random_bits_partitionable(2 * g));
            float g1 = gumbel_from_bits(random_bits_partitionable(2 * g + 1));
            float l0 = logf(p0 + 1e-12f) + g0;
            float l1 = logf(pp1 + 1e-12f) + g1;
            samp = (l1 > l0) ? 1 : 0;
            ind[g] = (samp == targets[g]) ? 1.0f : 0.0f;
        }
        samp = __shfl(samp, 0);

        // ---- phase 2: Q-MLP (128->8 relu ->16 softmax) + feature_mask ----
        if (l < 40) {
            int p = l >> 2, s = l & 3;
            float ua = pb1[2 * s], ub = pb1[2 * s + 1];
            const float4* E4 = (const float4*)&El[p * ELPAD];
            #pragma unroll 4
            for (int k4 = 0; k4 < 32; k4++) {
                float4 e4 = E4[k4];
                float es[4] = {e4.x, e4.y, e4.z, e4.w};
                #pragma unroll
                for (int kk = 0; kk < 4; kk++) {
                    int k = k4 * 4 + kk;
                    ua = fmaf(es[kk], p1[k * PHID + 2 * s], ua);
                    ub = fmaf(es[kk], p1[k * PHID + 2 * s + 1], ub);
                }
            }
            ua = fmaxf(ua, 0.f);
            ub = fmaxf(ub, 0.f);
            float v[NF];
            #pragma unroll
            for (int f = 0; f < NF; f++) {
                v[f] = pb2[f] * 0.25f;  // bias split: reduce over 4 lanes adds it once
                v[f] = fmaf(ua, p2[(2 * s) * NF + f], v[f]);
                v[f] = fmaf(ub, p2[(2 * s + 1) * NF + f], v[f]);
            }
            #pragma unroll
            for (int f = 0; f < NF; f++) {
                v[f] += __shfl_xor(v[f], 1);
                v[f] += __shfl_xor(v[f], 2);
            }
            float m = v[0];
            #pragma unroll
            for (int f = 1; f < NF; f++) m = fmaxf(m, v[f]);
            float ssum = 0.f, qv[NF];
            #pragma unroll
            for (int f = 0; f < NF; f++) { qv[f] = expf(v[f] - m); ssum += qv[f]; }
            float inv = 1.0f / ssum;
            #pragma unroll
            for (int f = 0; f < NF; f++) qv[f] *= inv;
            float* Qo = Q + ((size_t)g * NC + p) * NF;
            ((float4*)Qo)[s] = make_float4(qv[s * 4], qv[s * 4 + 1], qv[s * 4 + 2], qv[s * 4 + 3]);
            float fmv = 0.f;
            #pragma unroll
            for (int f = 0; f < NF; f++) {
                float cv = __shfl(corr_lf, samp * NF + f);
                fmv = fmaf(qv[f], cv, fmv);
            }
            if (s == 0) fmbuf[p] = fmv;
        }
    }
    __syncthreads();

    if (tid < 64) {
        // ---- phase 3: pred2 ----
        float b0 = 0.f, b1acc = 0.f;
        #pragma unroll
        for (int i = 0; i < 20; i++) {
            int idx = i * 64 + l;
            float e = El[(idx >> 7) * ELPAD + (idx & 127)] * fmbuf[idx >> 7];
            float2 w = wf2[idx];
            b0 = fmaf(e, w.x, b0);
            b1acc = fmaf(e, w.y, b1acc);
        }
        #pragma unroll
        for (int off = 32; off > 0; off >>= 1) {
            b0 += __shfl_down(b0, off);
            b1acc += __shfl_down(b1acc, off);
        }
        if (l == 0) {
            pred2[g * 2] = b0 + bf[0];
            pred2[g * 2 + 1] = b1acc + bf[1];
        }
    }
}

extern "C" void kernel_launch(void* const* d_in, const int* in_sizes, int n_in,
                              void* d_out, int out_size, void* d_ws, size_t ws_size,
                              hipStream_t stream) {
    const float* H       = (const float*)d_in[0];
    // d_in[1] = batch (implied by n/125, unused)
    const int*   targets = (const int*)d_in[2];
    const float* w1      = (const float*)d_in[3];
    const float* b1      = (const float*)d_in[4];
    const float* w2      = (const float*)d_in[5];
    const float* b2      = (const float*)d_in[6];
    const float* wf      = (const float*)d_in[7];
    const float* bf      = (const float*)d_in[8];
    const float* p1      = (const float*)d_in[9];
    const float* pb1     = (const float*)d_in[10];
    const float* p2      = (const float*)d_in[11];
    const float* pb2     = (const float*)d_in[12];
    const float* ci      = (const float*)d_in[13];
    const float* cr      = (const float*)d_in[14];

    float* out   = (float*)d_out;
    float* pred1 = out + OFF_PRED1;
    float* pred2 = out + OFF_PRED2;
    float* ind   = out + OFF_IND;
    float* S     = out + OFF_S;
    float* E     = out + OFF_E;
    float* Q     = out + OFF_Q;

    short* fragHi = (short*)d_ws;                    // 20480 B
    short* fragLo = (short*)((char*)d_ws + 20480);   // 20480 B

    k_split_w1<<<40, 256, 0, stream>>>(w1, fragHi, fragLo);
    k_node_mlp<<<NN / 64, 256, 0, stream>>>(H, fragHi, fragLo, b1, w2, b2, S);
    k_E_tail<<<NG, 1024, 0, stream>>>(H, S, wf, bf, targets, p1, pb1, p2, pb2,
                                      ci, cr, E, pred1, pred2, ind, Q);
}

// Round 13
// 131.976 us; speedup vs baseline: 1.0044x; 1.0044x over previous
//
#include <hip/hip_runtime.h>

#define NN 64000
#define NG 512
#define NPG 125
#define DIM 128
#define NC 10
#define SHID 69
#define NF 16
#define PHID 8
#define ELPAD 132   // E rows padded 128->132 in LDS
#define EPSTR 11    // Epart per-d stride (odd -> conflict-free)

// output float offsets (concatenated tuple, row-major)
#define OFF_PRED1 0
#define OFF_PRED2 1024
#define OFF_IND   2048
#define OFF_S     2560
#define OFF_E     642560
#define OFF_Q     1297920

typedef __attribute__((ext_vector_type(8))) short short8;   // 8 bf16 (4 VGPRs)
typedef __attribute__((ext_vector_type(4))) float f32x4;    // MFMA C/D

// ---------------- threefry2x32 (JAX-exact, key = (0, 42)) ----------------
__device__ __forceinline__ unsigned rotl32(unsigned x, int r) {
    return (x << r) | (x >> (32 - r));
}

__device__ __forceinline__ void threefry_0_42(unsigned x0, unsigned x1,
                                              unsigned& o0, unsigned& o1) {
    const unsigned k0 = 0u, k1 = 42u;
    const unsigned k2 = k0 ^ k1 ^ 0x1BD11BDAu;
    unsigned ks[3] = {k0, k1, k2};
    const int R0[4] = {13, 15, 26, 6};
    const int R1[4] = {17, 29, 16, 24};
    x0 += k0; x1 += k1;
    #pragma unroll
    for (int i = 0; i < 5; i++) {
        const int* R = (i & 1) ? R1 : R0;
        #pragma unroll
        for (int r = 0; r < 4; r++) {
            x0 += x1;
            x1 = rotl32(x1, R[r]);
            x1 ^= x0;
        }
        x0 += ks[(i + 1) % 3];
        x1 += ks[(i + 2) % 3] + (unsigned)(i + 1);
    }
    o0 = x0; o1 = x1;
}

// jax_threefry_partitionable: element i -> counter (0, i); bits = o0 ^ o1. (verified R2)
__device__ __forceinline__ unsigned random_bits_partitionable(unsigned i) {
    unsigned o0, o1;
    threefry_0_42(0u, i, o0, o1);
    return o0 ^ o1;
}

__device__ __forceinline__ float gumbel_from_bits(unsigned bits) {
    float f = __uint_as_float((bits >> 9) | 0x3f800000u) - 1.0f;  // [0,1)
    if (f <= 0.0f) f = 1.1754943508222875e-38f;                   // minval=tiny
    return -logf(-logf(f));
}

#define R10(M) M(0) M(1) M(2) M(3) M(4) M(5) M(6) M(7) M(8) M(9)

// ---------------- K0: pre-split w1 into hi/lo bf16 B-fragments in d_ws ----------------
// slot s = (jt*4+ks)*64 + lane; element i in [0,8): j = jt*16+(l&15),
// k = ks*32+((l>>4)&3)*8+i. (verified R11/R12)
__global__ __launch_bounds__(256) void k_split_w1(
    const float* __restrict__ w1, short* __restrict__ fragHi,
    short* __restrict__ fragLo) {
    int e = blockIdx.x * 256 + threadIdx.x;   // < 10240
    int s = e >> 3, i = e & 7;
    int jt = s >> 8, ks = (s >> 6) & 3, l = s & 63;
    int j = jt * 16 + (l & 15);
    int kb = ks * 32 + ((l >> 4) & 3) * 8;
    float x = (j < SHID) ? w1[(kb + i) * SHID + j] : 0.0f;
    unsigned u = __float_as_uint(x);
    short hi = (short)(u >> 16);
    float hf = __uint_as_float(u & 0xFFFF0000u);
    short lo = (short)(__float_as_uint(x - hf) >> 16);
    fragHi[s * 8 + i] = hi;
    fragLo[s * 8 + i] = lo;
}

// ---------------- Fused kernel: block = graph (512 threads = 8 waves) ----------------
// Phase 1: S via split-bf16 MFMA (wave w: nodes w*16..w*16+15, wave 7 masked);
//          layer 2 in registers + shfl_xor over the 16-lane quad group.
// Phase 2: E = S^T H (H L2-hot from phase 1, S from LDS Sl).
// Phase 3: verified tail (corr, pred1, threefry sample, Q, fm, pred2) on wave 0.
__global__ __launch_bounds__(512, 2) void k_fused(
    const float* __restrict__ H, const short* __restrict__ fragHi,
    const short* __restrict__ fragLo,
    const float* __restrict__ b1, const float* __restrict__ w2,
    const float* __restrict__ b2,
    const float* __restrict__ wf, const float* __restrict__ bf,
    const int* __restrict__ targets,
    const float* __restrict__ p1, const float* __restrict__ pb1,
    const float* __restrict__ p2, const float* __restrict__ pb2,
    const float* __restrict__ ci, const float* __restrict__ cr,
    float* __restrict__ S, float* __restrict__ E,
    float* __restrict__ pred1, float* __restrict__ pred2,
    float* __restrict__ ind, float* __restrict__ Q) {
    __shared__ __align__(8) float Sl[128 * NC];      // 5120 B (rows >=125 zeroed)
    __shared__ float Epart[3 * 128 * EPSTR];         // 16896 B
    __shared__ __align__(16) float El[NC * ELPAD];   // 5280 B
    __shared__ float fmbuf[NC];
    int g = blockIdx.x, tid = threadIdx.x;
    int w = tid >> 6, l = tid & 63;
    int lm = l & 15, quad = (l >> 4) & 3;

    // ======== Phase 1: per-node MLP + softmax -> Sl / S ========
    {
        int nload = w * 16 + lm;                         // 0..127
        int nclamp = min(nload, NPG - 1);
        const float* Hp = H + ((size_t)g * NPG + nclamp) * DIM + quad * 8;

        // A fragments (hi/lo), 4 k-steps (m120-verified layout)
        short8 aHi[4], aLo[4];
        #pragma unroll
        for (int ks = 0; ks < 4; ks++) {
            float4 x0 = *(const float4*)(Hp + ks * 32);
            float4 x1 = *(const float4*)(Hp + ks * 32 + 4);
            float xs[8] = {x0.x, x0.y, x0.z, x0.w, x1.x, x1.y, x1.z, x1.w};
            #pragma unroll
            for (int i = 0; i < 8; i++) {
                unsigned u = __float_as_uint(xs[i]);
                aHi[ks][i] = (short)(u >> 16);
                float lo = xs[i] - __uint_as_float(u & 0xFFFF0000u);
                aLo[ks][i] = (short)(__float_as_uint(lo) >> 16);
            }
        }

        // MFMA: 5 j-tiles x 4 k-steps x 3 (hihi, lohi, hilo)
        f32x4 acc[5];
        #pragma unroll
        for (int jt = 0; jt < 5; jt++) {
            f32x4 a = {0.f, 0.f, 0.f, 0.f};
            #pragma unroll
            for (int ks = 0; ks < 4; ks++) {
                int slot = (jt * 4 + ks) * 64 + l;
                short8 bh = *(const short8*)(fragHi + (size_t)slot * 8);
                short8 bl = *(const short8*)(fragLo + (size_t)slot * 8);
                a = __builtin_amdgcn_mfma_f32_16x16x32_bf16(aHi[ks], bh, a, 0, 0, 0);
                a = __builtin_amdgcn_mfma_f32_16x16x32_bf16(aLo[ks], bh, a, 0, 0, 0);
                a = __builtin_amdgcn_mfma_f32_16x16x32_bf16(aHi[ks], bl, a, 0, 0, 0);
            }
            acc[jt] = a;
        }

        // Layer 2 in registers: lane covers j = jt*16+lm (5 values) for its
        // 4 C/D rows (nodes quad*4+r). C/D layout m89-verified.
        float lg[4][10] = {};
        #pragma unroll
        for (int jt = 0; jt < 5; jt++) {
            int j = jt * 16 + lm;
            bool jv = (j < SHID);
            int jx = jv ? j : 0;
            float bj = b1[jx];
            float wv[10];
            const float* w2r = w2 + jx * NC;
            #pragma unroll
            for (int c = 0; c < NC; c++) wv[c] = w2r[c];
            #pragma unroll
            for (int r = 0; r < 4; r++) {
                float tr = jv ? fmaxf(acc[jt][r] + bj, 0.0f) : 0.0f;
                #pragma unroll
                for (int c = 0; c < NC; c++) lg[r][c] = fmaf(tr, wv[c], lg[r][c]);
            }
        }
        // butterfly over the 16-lane quad group completes the j-sum
        #pragma unroll
        for (int r = 0; r < 4; r++) {
            #pragma unroll
            for (int c = 0; c < NC; c++) {
                lg[r][c] += __shfl_xor(lg[r][c], 1);
                lg[r][c] += __shfl_xor(lg[r][c], 2);
                lg[r][c] += __shfl_xor(lg[r][c], 4);
                lg[r][c] += __shfl_xor(lg[r][c], 8);
            }
        }

        if (lm == 0) {
            #pragma unroll
            for (int r = 0; r < 4; r++) {
                int nloc = w * 16 + quad * 4 + r;        // 0..127
                bool valid = (nloc < NPG);
                float s0 = lg[r][0] + b2[0], s1 = lg[r][1] + b2[1],
                      s2 = lg[r][2] + b2[2], s3 = lg[r][3] + b2[3],
                      s4 = lg[r][4] + b2[4], s5 = lg[r][5] + b2[5],
                      s6 = lg[r][6] + b2[6], s7 = lg[r][7] + b2[7],
                      s8 = lg[r][8] + b2[8], s9 = lg[r][9] + b2[9];
                float m = fmaxf(fmaxf(fmaxf(s0, s1), fmaxf(s2, s3)),
                                fmaxf(fmaxf(fmaxf(s4, s5), fmaxf(s6, s7)),
                                      fmaxf(s8, s9)));
                float e0 = expf(s0 - m), e1 = expf(s1 - m), e2 = expf(s2 - m),
                      e3 = expf(s3 - m), e4 = expf(s4 - m), e5 = expf(s5 - m),
                      e6 = expf(s6 - m), e7 = expf(s7 - m), e8 = expf(s8 - m),
                      e9 = expf(s9 - m);
                float ssum = ((e0 + e1) + (e2 + e3)) + ((e4 + e5) + (e6 + e7)) + (e8 + e9);
                float inv = valid ? (1.0f / ssum) : 0.0f;  // invalid rows -> 0 in Sl
                float v0 = e0 * inv, v1 = e1 * inv, v2 = e2 * inv, v3 = e3 * inv,
                      v4 = e4 * inv, v5 = e5 * inv, v6 = e6 * inv, v7 = e7 * inv,
                      v8 = e8 * inv, v9 = e9 * inv;
                float* slp = &Sl[nloc * NC];
                slp[0] = v0; slp[1] = v1; slp[2] = v2; slp[3] = v3; slp[4] = v4;
                slp[5] = v5; slp[6] = v6; slp[7] = v7; slp[8] = v8; slp[9] = v9;
                if (valid) {
                    float2* Sp2 = (float2*)(S + ((size_t)g * NPG + nloc) * NC);
                    Sp2[0] = make_float2(v0, v1);
                    Sp2[1] = make_float2(v2, v3);
                    Sp2[2] = make_float2(v4, v5);
                    Sp2[3] = make_float2(v6, v7);
                    Sp2[4] = make_float2(v8, v9);
                }
            }
        }
    }
    __syncthreads();

    // ======== Phase 2: E[c][d] = sum_n Sl[n][c] * H[n][d]  (H L2-hot) ========
    {
        int q = tid >> 7;       // node quarter 0..3 (32 nodes each)
        int d = tid & 127;
        const float* Hg = H + (size_t)g * NPG * DIM + d;

        #define DECLA(c) float a##c = 0.f;
        R10(DECLA)
        #undef DECLA
        int n0 = q * 32;
        #pragma unroll
        for (int ib = 0; ib < 32; ib += 8) {
            float h[8];
            #pragma unroll
            for (int u = 0; u < 8; u++) {
                int nh = min(n0 + ib + u, NPG - 1);   // rows >=125 have Sl=0
                h[u] = Hg[(size_t)nh * DIM];
            }
            #pragma unroll
            for (int u = 0; u < 8; u++) {
                const float2* S2 = (const float2*)(Sl + (n0 + ib + u) * NC);
                float2 s01 = S2[0], s23 = S2[1], s45 = S2[2], s67 = S2[3], s89 = S2[4];
                a0 = fmaf(s01.x, h[u], a0); a1 = fmaf(s01.y, h[u], a1);
                a2 = fmaf(s23.x, h[u], a2); a3 = fmaf(s23.y, h[u], a3);
                a4 = fmaf(s45.x, h[u], a4); a5 = fmaf(s45.y, h[u], a5);
                a6 = fmaf(s67.x, h[u], a6); a7 = fmaf(s67.y, h[u], a7);
                a8 = fmaf(s89.x, h[u], a8); a9 = fmaf(s89.y, h[u], a9);
            }
        }
        if (q > 0) {
            float* ep = &Epart[((q - 1) * 128 + d) * EPSTR];
            #define STP(c) ep[c] = a##c;
            R10(STP)
            #undef STP
        }
        __syncthreads();
        if (q == 0) {
            float* Eo = E + (size_t)g * (NC * DIM) + d;
            #pragma unroll
            for (int k = 0; k < 3; k++) {
                const float* ep = &Epart[(k * 128 + d) * EPSTR];
                a0 += ep[0]; a1 += ep[1]; a2 += ep[2]; a3 += ep[3]; a4 += ep[4];
                a5 += ep[5]; a6 += ep[6]; a7 += ep[7]; a8 += ep[8]; a9 += ep[9];
            }
            #define CMB(c) { El[(c) * ELPAD + d] = a##c; Eo[(c) * DIM] = a##c; }
            R10(CMB)
            #undef CMB
        }
    }
    __syncthreads();

    // ======== Phase 3: verified tail on wave 0 ========
    const float2* wf2 = (const float2*)wf;
    int lt = tid;
    int samp = 0;
    float corr_lf = 0.f;

    if (tid < 64) {
        // ---- corr: lane lt<32 computes corr[i=lt>>4][f=lt&15] ----
        if (lt < 32) {
            int i = lt >> 4, f = lt & 15;
            float a = ci[f], b = ci[NF + f];
            float mm = fmaxf(a, b);
            float ea = expf(a - mm), eb = expf(b - mm);
            float inter = expf(ci[i * NF + f] - mm) / (ea + eb);
            float mi = -1e30f;
            for (int j = 0; j < NF; j++) mi = fmaxf(mi, cr[i * NF + j]);
            float ri = 0.f;
            for (int j = 0; j < NF; j++) ri += expf(cr[i * NF + j] - mi);
            float intra = expf(cr[i * NF + f] - mi) / ri;
            corr_lf = inter * intra;
        }

        // ---- pred1 + softmax + gumbel sample + ind ----
        float a0 = 0.f, a1 = 0.f;
        #pragma unroll
        for (int i = 0; i < 20; i++) {
            int idx = i * 64 + lt;
            float e = El[(idx >> 7) * ELPAD + (idx & 127)];
            float2 wv = wf2[idx];
            a0 = fmaf(e, wv.x, a0);
            a1 = fmaf(e, wv.y, a1);
        }
        #pragma unroll
        for (int off = 32; off > 0; off >>= 1) {
            a0 += __shfl_down(a0, off);
            a1 += __shfl_down(a1, off);
        }
        if (lt == 0) {
            float y0 = a0 + bf[0], y1 = a1 + bf[1];
            pred1[g * 2] = y0;
            pred1[g * 2 + 1] = y1;
            float m = fmaxf(y0, y1);
            float e0 = expf(y0 - m), e1 = expf(y1 - m), s = e0 + e1;
            float p0 = e0 / s, pp1 = e1 / s;
            float g0 = gumbel_from_bits(random_bits_partitionable(2 * g));
            float g1 = gumbel_from_bits(random_bits_partitionable(2 * g + 1));
            float l0 = logf(p0 + 1e-12f) + g0;
            float l1 = logf(pp1 + 1e-12f) + g1;
            samp = (l1 > l0) ? 1 : 0;
            ind[g] = (samp == targets[g]) ? 1.0f : 0.0f;
        }
        samp = __shfl(samp, 0);

        // ---- Q-MLP (128->8 relu ->16 softmax) + feature_mask ----
        if (lt < 40) {
            int p = lt >> 2, s = lt & 3;
            float ua = pb1[2 * s], ub = pb1[2 * s + 1];
            const float4* E4 = (const float4*)&El[p * ELPAD];
            #pragma unroll 4
            for (int k4 = 0; k4 < 32; k4++) {
                float4 e4 = E4[k4];
                float es[4] = {e4.x, e4.y, e4.z, e4.w};
                #pragma unroll
                for (int kk = 0; kk < 4; kk++) {
                    int k = k4 * 4 + kk;
                    ua = fmaf(es[kk], p1[k * PHID + 2 * s], ua);
                    ub = fmaf(es[kk], p1[k * PHID + 2 * s + 1], ub);
                }
            }
            ua = fmaxf(ua, 0.f);
            ub = fmaxf(ub, 0.f);
            float v[NF];
            #pragma unroll
            for (int f = 0; f < NF; f++) {
                v[f] = pb2[f] * 0.25f;  // bias split: reduce over 4 lanes adds it once
                v[f] = fmaf(ua, p2[(2 * s) * NF + f], v[f]);
                v[f] = fmaf(ub, p2[(2 * s + 1) * NF + f], v[f]);
            }
            #pragma unroll
            for (int f = 0; f < NF; f++) {
                v[f] += __shfl_xor(v[f], 1);
                v[f] += __shfl_xor(v[f], 2);
            }
            float m = v[0];
            #pragma unroll
            for (int f = 1; f < NF; f++) m = fmaxf(m, v[f]);
            float ssum = 0.f, qv[NF];
            #pragma unroll
            for (int f = 0; f < NF; f++) { qv[f] = expf(v[f] - m); ssum += qv[f]; }
            float inv = 1.0f / ssum;
            #pragma unroll
            for (int f = 0; f < NF; f++) qv[f] *= inv;
            float* Qo = Q + ((size_t)g * NC + p) * NF;
            ((float4*)Qo)[s] = make_float4(qv[s * 4], qv[s * 4 + 1], qv[s * 4 + 2], qv[s * 4 + 3]);
            float fmv = 0.f;
            #pragma unroll
            for (int f = 0; f < NF; f++) {
                float cv = __shfl(corr_lf, samp * NF + f);
                fmv = fmaf(qv[f], cv, fmv);
            }
            if (s == 0) fmbuf[p] = fmv;
        }
    }
    __syncthreads();

    if (tid < 64) {
        // ---- pred2 ----
        float b0 = 0.f, b1acc = 0.f;
        #pragma unroll
        for (int i = 0; i < 20; i++) {
            int idx = i * 64 + lt;
            float e = El[(idx >> 7) * ELPAD + (idx & 127)] * fmbuf[idx >> 7];
            float2 wv = wf2[idx];
            b0 = fmaf(e, wv.x, b0);
            b1acc = fmaf(e, wv.y, b1acc);
        }
        #pragma unroll
        for (int off = 32; off > 0; off >>= 1) {
            b0 += __shfl_down(b0, off);
            b1acc += __shfl_down(b1acc, off);
        }
        if (lt == 0) {
            pred2[g * 2] = b0 + bf[0];
            pred2[g * 2 + 1] = b1acc + bf[1];
        }
    }
}

extern "C" void kernel_launch(void* const* d_in, const int* in_sizes, int n_in,
                              void* d_out, int out_size, void* d_ws, size_t ws_size,
                              hipStream_t stream) {
    const float* H       = (const float*)d_in[0];
    // d_in[1] = batch (implied by n/125, unused)
    const int*   targets = (const int*)d_in[2];
    const float* w1      = (const float*)d_in[3];
    const float* b1      = (const float*)d_in[4];
    const float* w2      = (const float*)d_in[5];
    const float* b2      = (const float*)d_in[6];
    const float* wf      = (const float*)d_in[7];
    const float* bf      = (const float*)d_in[8];
    const float* p1      = (const float*)d_in[9];
    const float* pb1     = (const float*)d_in[10];
    const float* p2      = (const float*)d_in[11];
    const float* pb2     = (const float*)d_in[12];
    const float* ci      = (const float*)d_in[13];
    const float* cr      = (const float*)d_in[14];

    float* out   = (float*)d_out;
    float* pred1 = out + OFF_PRED1;
    float* pred2 = out + OFF_PRED2;
    float* ind   = out + OFF_IND;
    float* S     = out + OFF_S;
    float* E     = out + OFF_E;
    float* Q     = out + OFF_Q;

    short* fragHi = (short*)d_ws;                    // 20480 B
    short* fragLo = (short*)((char*)d_ws + 20480);   // 20480 B

    k_split_w1<<<40, 256, 0, stream>>>(w1, fragHi, fragLo);
    k_fused<<<NG, 512, 0, stream>>>(H, fragHi, fragLo, b1, w2, b2, wf, bf,
                                    targets, p1, pb1, p2, pb2, ci, cr,
                                    S, E, pred1, pred2, ind, Q);
}

// Round 14
// 125.705 us; speedup vs baseline: 1.0545x; 1.0499x over previous
//
#include <hip/hip_runtime.h>

#define NN 64000
#define NG 512
#define NPG 125
#define DIM 128
#define NC 10
#define SHID 69
#define NF 16
#define PHID 8
#define ELPAD 132   // E rows padded 128->132 in LDS (k_E_tail)
#define TSTR 85     // Ts row stride (odd -> conflict-free)
#define PSTR 41     // Ps row stride (odd -> conflict-free)

// output float offsets (concatenated tuple, row-major)
#define OFF_PRED1 0
#define OFF_PRED2 1024
#define OFF_IND   2048
#define OFF_S     2560
#define OFF_E     642560
#define OFF_Q     1297920

typedef __attribute__((ext_vector_type(8))) short short8;   // 8 bf16 (4 VGPRs)
typedef __attribute__((ext_vector_type(4))) float f32x4;    // MFMA C/D

// ---------------- threefry2x32 (JAX-exact, key = (0, 42)) ----------------
__device__ __forceinline__ unsigned rotl32(unsigned x, int r) {
    return (x << r) | (x >> (32 - r));
}

__device__ __forceinline__ void threefry_0_42(unsigned x0, unsigned x1,
                                              unsigned& o0, unsigned& o1) {
    const unsigned k0 = 0u, k1 = 42u;
    const unsigned k2 = k0 ^ k1 ^ 0x1BD11BDAu;
    unsigned ks[3] = {k0, k1, k2};
    const int R0[4] = {13, 15, 26, 6};
    const int R1[4] = {17, 29, 16, 24};
    x0 += k0; x1 += k1;
    #pragma unroll
    for (int i = 0; i < 5; i++) {
        const int* R = (i & 1) ? R1 : R0;
        #pragma unroll
        for (int r = 0; r < 4; r++) {
            x0 += x1;
            x1 = rotl32(x1, R[r]);
            x1 ^= x0;
        }
        x0 += ks[(i + 1) % 3];
        x1 += ks[(i + 2) % 3] + (unsigned)(i + 1);
    }
    o0 = x0; o1 = x1;
}

// jax_threefry_partitionable: element i -> counter (0, i); bits = o0 ^ o1. (verified R2)
__device__ __forceinline__ unsigned random_bits_partitionable(unsigned i) {
    unsigned o0, o1;
    threefry_0_42(0u, i, o0, o1);
    return o0 ^ o1;
}

__device__ __forceinline__ float gumbel_from_bits(unsigned bits) {
    float f = __uint_as_float((bits >> 9) | 0x3f800000u) - 1.0f;  // [0,1)
    if (f <= 0.0f) f = 1.1754943508222875e-38f;                   // minval=tiny
    return -logf(-logf(f));
}

#define R10(M) M(0) M(1) M(2) M(3) M(4) M(5) M(6) M(7) M(8) M(9)

// ---------------- K1: per-node MLP 128->69(relu)->10 + softmax (split-bf16 MFMA) ----------------
// Block = 64 nodes, 256 threads = 4 waves; wave w owns nodes [w*16, w*16+16).
// Layer 1: t = H@w1 via mfma_f32_16x16x32_bf16, split-bf16 (hi+lo, 3 MFMA/tile,
// err ~2^-16). w1 pre-split to fragment-ordered LDS (40 KB), aliased by Ts/Ps
// afterwards. M=16 nodes, N=80 (5 j-tiles, pad>=69 zero), K=128 (4 steps).
// A layout: A[m=lane&15][k=(lane>>4)*8+i] (m120-verified). C/D: row=(lane>>4)*4+reg,
// col=lane&15 (m89-verified). Layer 2 + softmax: R9's verified Ts->Ps->combine.
// [R11 bench: 128.2 us total; best measured config of the session.]
__global__ __launch_bounds__(256, 4) void k_node_mlp(
    const float* __restrict__ H, const float* __restrict__ w1,
    const float* __restrict__ b1, const float* __restrict__ w2,
    const float* __restrict__ b2, float* __restrict__ S) {
    __shared__ __align__(16) char lds[40960];
    short* fragHi = (short*)lds;             // 1280 slots x 8 shorts (20480 B)
    short* fragLo = (short*)(lds + 20480);   // 20480 B
    int tid = threadIdx.x;

    // ---- stage w1 as hi/lo B-fragments: slot = (jt*4+ks)*64 + lane ----
    for (int s = tid; s < 1280; s += 256) {
        int jt = s >> 8, ks = (s >> 6) & 3, l = s & 63;
        int j = jt * 16 + (l & 15);
        int kb = ks * 32 + ((l >> 4) & 3) * 8;
        short8 vh, vl;
        #pragma unroll
        for (int i = 0; i < 8; i++) {
            float x = (j < SHID) ? w1[(kb + i) * SHID + j] : 0.0f;
            unsigned u = __float_as_uint(x);
            vh[i] = (short)(u >> 16);
            float hf = __uint_as_float(u & 0xFFFF0000u);
            float lo = x - hf;                       // exact
            vl[i] = (short)(__float_as_uint(lo) >> 16);
        }
        *(short8*)(fragHi + (size_t)s * 8) = vh;
        *(short8*)(fragLo + (size_t)s * 8) = vl;
    }
    __syncthreads();

    int w = tid >> 6, l = tid & 63;
    int node = blockIdx.x * 64 + w * 16 + (l & 15);
    const float* Hp = H + (size_t)node * DIM + ((l >> 4) & 3) * 8;

    // ---- A fragments (hi/lo) for 4 k-steps ----
    short8 aHi[4], aLo[4];
    #pragma unroll
    for (int ks = 0; ks < 4; ks++) {
        float4 x0 = *(const float4*)(Hp + ks * 32);
        float4 x1 = *(const float4*)(Hp + ks * 32 + 4);
        float xs[8] = {x0.x, x0.y, x0.z, x0.w, x1.x, x1.y, x1.z, x1.w};
        #pragma unroll
        for (int i = 0; i < 8; i++) {
            unsigned u = __float_as_uint(xs[i]);
            aHi[ks][i] = (short)(u >> 16);
            float lo = xs[i] - __uint_as_float(u & 0xFFFF0000u);
            aLo[ks][i] = (short)(__float_as_uint(lo) >> 16);
        }
    }

    // ---- MFMA: 5 j-tiles x 4 k-steps x 3 (hihi, lohi, hilo) ----
    f32x4 acc[5];
    #pragma unroll
    for (int jt = 0; jt < 5; jt++) {
        f32x4 a = {0.f, 0.f, 0.f, 0.f};
        #pragma unroll
        for (int ks = 0; ks < 4; ks++) {
            int slot = (jt * 4 + ks) * 64 + l;
            short8 bh = *(short8*)(fragHi + (size_t)slot * 8);
            short8 bl = *(short8*)(fragLo + (size_t)slot * 8);
            a = __builtin_amdgcn_mfma_f32_16x16x32_bf16(aHi[ks], bh, a, 0, 0, 0);
            a = __builtin_amdgcn_mfma_f32_16x16x32_bf16(aLo[ks], bh, a, 0, 0, 0);
            a = __builtin_amdgcn_mfma_f32_16x16x32_bf16(aHi[ks], bl, a, 0, 0, 0);
        }
        acc[jt] = a;
    }
    __syncthreads();   // all frag reads done -> safe to alias LDS

    // ---- relu(t + b1) into Ts[64][TSTR] (pad j>=69 -> 0) ----
    float* Ts = (float*)lds;                  // 64*85*4 = 21760 B
    float* Ps = (float*)(lds + 21760);        // 64*41*4 = 10496 B
    #pragma unroll
    for (int jt = 0; jt < 5; jt++) {
        int j = jt * 16 + (l & 15);
        float bj = (j < SHID) ? b1[j] : 0.0f;
        #pragma unroll
        for (int r = 0; r < 4; r++) {
            int m = w * 16 + ((l >> 4) & 3) * 4 + r;
            float tv = acc[jt][r];
            Ts[m * TSTR + j] = (j < SHID) ? fmaxf(tv + bj, 0.0f) : 0.0f;
        }
    }
    __syncthreads();

    // ---- layer 2 partials: thread (n = tid&63, q = tid>>6), j in [q*18, q*18+18) ----
    {
        int n = tid & 63, q = tid >> 6;
        float lg[NC] = {};
        for (int jj = 0; jj < 18; jj++) {
            int j = q * 18 + jj;               // < 72; Ts is 0 for j >= 69
            int jx = (j < SHID) ? j : (SHID - 1);
            float tr = Ts[n * TSTR + j];
            const float* w2r = w2 + jx * NC;   // wave-uniform -> s_load
            #pragma unroll
            for (int c = 0; c < NC; c++) lg[c] = fmaf(tr, w2r[c], lg[c]);
        }
        #pragma unroll
        for (int c = 0; c < NC; c++) Ps[n * PSTR + q * NC + c] = lg[c];
    }
    __syncthreads();

    if (tid < 64) {
        int n = tid;
        const float* pr = &Ps[n * PSTR];
        #define LD(c) float s##c = pr[c] + pr[10 + c] + pr[20 + c] + pr[30 + c] + b2[c];
        R10(LD)
        #undef LD
        float m = fmaxf(fmaxf(fmaxf(s0, s1), fmaxf(s2, s3)),
                        fmaxf(fmaxf(fmaxf(s4, s5), fmaxf(s6, s7)), fmaxf(s8, s9)));
        float e0 = expf(s0 - m), e1 = expf(s1 - m), e2 = expf(s2 - m),
              e3 = expf(s3 - m), e4 = expf(s4 - m), e5 = expf(s5 - m),
              e6 = expf(s6 - m), e7 = expf(s7 - m), e8 = expf(s8 - m),
              e9 = expf(s9 - m);
        float ssum = ((e0 + e1) + (e2 + e3)) + ((e4 + e5) + (e6 + e7)) + (e8 + e9);
        float inv = 1.0f / ssum;
        float2* Sp2 = (float2*)(S + ((size_t)blockIdx.x * 64 + n) * NC);
        Sp2[0] = make_float2(e0 * inv, e1 * inv);
        Sp2[1] = make_float2(e2 * inv, e3 * inv);
        Sp2[2] = make_float2(e4 * inv, e5 * inv);
        Sp2[3] = make_float2(e6 * inv, e7 * inv);
        Sp2[4] = make_float2(e8 * inv, e9 * inv);
    }
}

// ---------------- K2: fused E + tail (corr, pred1, sample, Q, fm, pred2) ----------------
// Block = graph, 512 threads = 4 node-quarters x 128 d. S read as float2
// (5 ds_read_b64/node), h loads batched x4; LDS combine; verified tail on wave 0.
__global__ __launch_bounds__(512, 2) void k_E_tail(
    const float* __restrict__ H, const float* __restrict__ S,
    const float* __restrict__ wf, const float* __restrict__ bf,
    const int* __restrict__ targets,
    const float* __restrict__ p1, const float* __restrict__ pb1,
    const float* __restrict__ p2, const float* __restrict__ pb2,
    const float* __restrict__ ci, const float* __restrict__ cr,
    float* __restrict__ E, float* __restrict__ pred1, float* __restrict__ pred2,
    float* __restrict__ ind, float* __restrict__ Q) {
    __shared__ __align__(8) float Sl[128 * NC];    // padded to 128 node rows
    __shared__ float Epart[3 * 128 * NC];          // quarters 1..3 partials
    __shared__ __align__(16) float El[NC * ELPAD];
    __shared__ float fmbuf[NC];
    int g = blockIdx.x, tid = threadIdx.x;

    const float* Sg = S + (size_t)g * NPG * NC;
    for (int i = tid; i < 128 * NC; i += 512) Sl[i] = (i < NPG * NC) ? Sg[i] : 0.0f;
    __syncthreads();

    int q = tid >> 7;       // node quarter 0..3
    int d = tid & 127;
    const float* Hg = H + (size_t)g * NPG * DIM + d;

    #define DECLA(c) float a##c = 0.f;
    R10(DECLA)
    #undef DECLA
    int n0 = q * 32;
    #pragma unroll
    for (int ib = 0; ib < 32; ib += 4) {
        float h[4];
        #pragma unroll
        for (int u = 0; u < 4; u++) {
            int nh = min(n0 + ib + u, NPG - 1);   // rows 125..127 have S=0
            h[u] = Hg[(size_t)nh * DIM];
        }
        #pragma unroll
        for (int u = 0; u < 4; u++) {
            const float2* S2 = (const float2*)(Sl + (n0 + ib + u) * NC);
            float2 s01 = S2[0], s23 = S2[1], s45 = S2[2], s67 = S2[3], s89 = S2[4];
            a0 = fmaf(s01.x, h[u], a0); a1 = fmaf(s01.y, h[u], a1);
            a2 = fmaf(s23.x, h[u], a2); a3 = fmaf(s23.y, h[u], a3);
            a4 = fmaf(s45.x, h[u], a4); a5 = fmaf(s45.y, h[u], a5);
            a6 = fmaf(s67.x, h[u], a6); a7 = fmaf(s67.y, h[u], a7);
            a8 = fmaf(s89.x, h[u], a8); a9 = fmaf(s89.y, h[u], a9);
        }
    }
    if (q > 0) {
        float* ep = &Epart[(q - 1) * 128 * NC + d * NC];
        #define STP(c) ep[c] = a##c;
        R10(STP)
        #undef STP
    }
    __syncthreads();
    if (q == 0) {
        const float* e1p = &Epart[d * NC];
        const float* e2p = &Epart[128 * NC + d * NC];
        const float* e3p = &Epart[2 * 128 * NC + d * NC];
        float* Eo = E + (size_t)g * (NC * DIM) + d;
        #define CMB(c) { a##c += e1p[c] + e2p[c] + e3p[c]; \
                         El[c * ELPAD + d] = a##c; Eo[c * DIM] = a##c; }
        R10(CMB)
        #undef CMB
    }
    __syncthreads();

    const float2* wf2 = (const float2*)wf;
    int l = tid;
    int samp = 0;
    float corr_lf = 0.f;

    if (tid < 64) {
        // ---- corr: lane l<32 computes corr[i=l>>4][f=l&15] ----
        if (l < 32) {
            int i = l >> 4, f = l & 15;
            float a = ci[f], b = ci[NF + f];
            float mm = fmaxf(a, b);
            float ea = expf(a - mm), eb = expf(b - mm);
            float inter = expf(ci[i * NF + f] - mm) / (ea + eb);
            float mi = -1e30f;
            for (int j = 0; j < NF; j++) mi = fmaxf(mi, cr[i * NF + j]);
            float ri = 0.f;
            for (int j = 0; j < NF; j++) ri += expf(cr[i * NF + j] - mi);
            float intra = expf(cr[i * NF + f] - mi) / ri;
            corr_lf = inter * intra;
        }

        // ---- phase 1: pred1 + softmax + gumbel sample + ind ----
        float a0 = 0.f, a1 = 0.f;
        #pragma unroll
        for (int i = 0; i < 20; i++) {
            int idx = i * 64 + l;
            float e = El[(idx >> 7) * ELPAD + (idx & 127)];
            float2 w = wf2[idx];
            a0 = fmaf(e, w.x, a0);
            a1 = fmaf(e, w.y, a1);
        }
        #pragma unroll
        for (int off = 32; off > 0; off >>= 1) {
            a0 += __shfl_down(a0, off);
            a1 += __shfl_down(a1, off);
        }
        if (l == 0) {
            float y0 = a0 + bf[0], y1 = a1 + bf[1];
            pred1[g * 2] = y0;
            pred1[g * 2 + 1] = y1;
            float m = fmaxf(y0, y1);
            float e0 = expf(y0 - m), e1 = expf(y1 - m), s = e0 + e1;
            float p0 = e0 / s, pp1 = e1 / s;
            float g0 = gumbel_from_bits(random_bits_partitionable(2 * g));
            float g1 = gumbel_from_bits(random_bits_partitionable(2 * g + 1));
            float l0 = logf(p0 + 1e-12f) + g0;
            float l1 = logf(pp1 + 1e-12f) + g1;
            samp = (l1 > l0) ? 1 : 0;
            ind[g] = (samp == targets[g]) ? 1.0f : 0.0f;
        }
        samp = __shfl(samp, 0);

        // ---- phase 2: Q-MLP (128->8 relu ->16 softmax) + feature_mask ----
        if (l < 40) {
            int p = l >> 2, s = l & 3;
            float ua = pb1[2 * s], ub = pb1[2 * s + 1];
            const float4* E4 = (const float4*)&El[p * ELPAD];
            #pragma unroll 4
            for (int k4 = 0; k4 < 32; k4++) {
                float4 e4 = E4[k4];
                float es[4] = {e4.x, e4.y, e4.z, e4.w};
                #pragma unroll
                for (int kk = 0; kk < 4; kk++) {
                    int k = k4 * 4 + kk;
                    ua = fmaf(es[kk], p1[k * PHID + 2 * s], ua);
                    ub = fmaf(es[kk], p1[k * PHID + 2 * s + 1], ub);
                }
            }
            ua = fmaxf(ua, 0.f);
            ub = fmaxf(ub, 0.f);
            float v[NF];
            #pragma unroll
            for (int f = 0; f < NF; f++) {
                v[f] = pb2[f] * 0.25f;  // bias split: reduce over 4 lanes adds it once
                v[f] = fmaf(ua, p2[(2 * s) * NF + f], v[f]);
                v[f] = fmaf(ub, p2[(2 * s + 1) * NF + f], v[f]);
            }
            #pragma unroll
            for (int f = 0; f < NF; f++) {
                v[f] += __shfl_xor(v[f], 1);
                v[f] += __shfl_xor(v[f], 2);
            }
            float m = v[0];
            #pragma unroll
            for (int f = 1; f < NF; f++) m = fmaxf(m, v[f]);
            float ssum = 0.f, qv[NF];
            #pragma unroll
            for (int f = 0; f < NF; f++) { qv[f] = expf(v[f] - m); ssum += qv[f]; }
            float inv = 1.0f / ssum;
            #pragma unroll
            for (int f = 0; f < NF; f++) qv[f] *= inv;
            float* Qo = Q + ((size_t)g * NC + p) * NF;
            ((float4*)Qo)[s] = make_float4(qv[s * 4], qv[s * 4 + 1], qv[s * 4 + 2], qv[s * 4 + 3]);
            float fmv = 0.f;
            #pragma unroll
            for (int f = 0; f < NF; f++) {
                float cv = __shfl(corr_lf, samp * NF + f);
                fmv = fmaf(qv[f], cv, fmv);
            }
            if (s == 0) fmbuf[p] = fmv;
        }
    }
    __syncthreads();

    if (tid < 64) {
        // ---- phase 3: pred2 ----
        float b0 = 0.f, b1acc = 0.f;
        #pragma unroll
        for (int i = 0; i < 20; i++) {
            int idx = i * 64 + l;
            float e = El[(idx >> 7) * ELPAD + (idx & 127)] * fmbuf[idx >> 7];
            float2 w = wf2[idx];
            b0 = fmaf(e, w.x, b0);
            b1acc = fmaf(e, w.y, b1acc);
        }
        #pragma unroll
        for (int off = 32; off > 0; off >>= 1) {
            b0 += __shfl_down(b0, off);
            b1acc += __shfl_down(b1acc, off);
        }
        if (l == 0) {
            pred2[g * 2] = b0 + bf[0];
            pred2[g * 2 + 1] = b1acc + bf[1];
        }
    }
}

extern "C" void kernel_launch(void* const* d_in, const int* in_sizes, int n_in,
                              void* d_out, int out_size, void* d_ws, size_t ws_size,
                              hipStream_t stream) {
    const float* H       = (const float*)d_in[0];
    // d_in[1] = batch (implied by n/125, unused)
    const int*   targets = (const int*)d_in[2];
    const float* w1      = (const float*)d_in[3];
    const float* b1      = (const float*)d_in[4];
    const float* w2      = (const float*)d_in[5];
    const float* b2      = (const float*)d_in[6];
    const float* wf      = (const float*)d_in[7];
    const float* bf      = (const float*)d_in[8];
    const float* p1      = (const float*)d_in[9];
    const float* pb1     = (const float*)d_in[10];
    const float* p2      = (const float*)d_in[11];
    const float* pb2     = (const float*)d_in[12];
    const float* ci      = (const float*)d_in[13];
    const float* cr      = (const float*)d_in[14];

    float* out   = (float*)d_out;
    float* pred1 = out + OFF_PRED1;
    float* pred2 = out + OFF_PRED2;
    float* ind   = out + OFF_IND;
    float* S     = out + OFF_S;
    float* E     = out + OFF_E;
    float* Q     = out + OFF_Q;

    k_node_mlp<<<NN / 64, 256, 0, stream>>>(H, w1, b1, w2, b2, S);
    k_E_tail<<<NG, 512, 0, stream>>>(H, S, wf, bf, targets, p1, pb1, p2, pb2,
                                     ci, cr, E, pred1, pred2, ind, Q);
}